// Round 6
// baseline (163.647 us; speedup 1.0000x reference)
//
#include <hip/hip_runtime.h>
#include <stdint.h>

#define NCAT  919
#define KDIM  400
#define NDIM  100
#define BK    32
#define NSTEP 13                 // ceil(400/32); step 12 has 16 valid k
#define KPAD  404                // LDS row (bf16): 808 B = 202 dwords; 202 mod 32 = 10 ->
                                 // 16 rows' b128 reads start at all 16 even banks: 2-way, free
#define NROWS 100                // NO N-pad: n=6 fragment clamps rows (see brow below)
                                 // LDS = 100*404*2 = 80800 B  ->  TWO blocks per CU

typedef float  f32x4  __attribute__((ext_vector_type(4)));
typedef __bf16 bf16x8 __attribute__((ext_vector_type(8)));
typedef __bf16 bf16x2 __attribute__((ext_vector_type(2)));

__global__ void __launch_bounds__(512, 4)   // 4 waves/EU = 2 blocks/CU -> VGPR <= 128
cat_dense(const float* __restrict__ in, const float* __restrict__ wt,
          const float* __restrict__ bias, float* __restrict__ out)
{
  __shared__ __bf16 wlds[NROWS * KPAD];      // 80800 B: 2 blocks/CU fit (161600 <= 163840)

  // Bijective XCD-aware swizzle (m204): 919 = 7*115 + 114. Consecutive categories
  // share an XCD L2 -> partial 128B output lines merge before writeback.
  const int ob   = blockIdx.x;
  const int xcd  = ob & 7;
  const int bidx = ob >> 3;
  const int c    = (xcd < 7 ? xcd * 115 : 805 + (xcd - 7) * 114) + bidx;

  const int tid  = threadIdx.x;
  const int lane = tid & 63;
  const int wave = tid >> 6;
  const int rl   = lane & 15;                // fragment row (A) / col (B/D)
  const int kg   = (lane >> 4) * 8;          // fragment k offset

  const size_t rstride = (size_t)NCAT * KDIM;
  const float* gA0 = in + (size_t)c * KDIM + (size_t)(wave * 32 + rl) * rstride;
  const float* gA1 = gA0 + (size_t)16 * rstride;
  const float* gW  = wt + (size_t)c * (KDIM * NDIM);

  // 2 prefetch slots (32 VGPR), distance-1..2: slot (t+1)&1 != t&1; reissue into
  // slot t&1 only AFTER its cvt (source order enforces the WAR dependency).
  f32x4 areg[2][2][2];

#define LOADA(T) do {                                                      \
    const int kb_ = (T) * BK + kg;                                         \
    const int s_  = (T) & 1;                                               \
    if (kb_ + 8 <= KDIM) {   /* per-lane K-tail mask (step 12, kg>=16) */  \
      areg[s_][0][0] = *(const f32x4*)(gA0 + kb_);                         \
      areg[s_][0][1] = *(const f32x4*)(gA0 + kb_ + 4);                     \
      areg[s_][1][0] = *(const f32x4*)(gA1 + kb_);                         \
      areg[s_][1][1] = *(const f32x4*)(gA1 + kb_ + 4);                     \
    } else {                                                               \
      areg[s_][0][0] = f32x4{0,0,0,0}; areg[s_][0][1] = f32x4{0,0,0,0};    \
      areg[s_][1][0] = f32x4{0,0,0,0}; areg[s_][1][1] = f32x4{0,0,0,0};    \
    }                                                                      \
  } while (0)

  // ---- prologue: A(0),A(1) in flight; they land during W staging ----
  LOADA(0);
  LOADA(1);

  // ---- stage full W_c -> LDS (transposed, bf16), ONCE ----
  // 5000 k-pair chunks: pc = kp*25 + nq; thread handles W[2kp][4nq..+3], W[2kp+1][...]
  #pragma unroll
  for (int i = 0; i < 10; ++i) {
    const int pc = tid + i * 512;
    if (pc < 5000) {
      const int kp = pc / 25;
      const int nq = pc - kp * 25;
      const int k  = kp * 2;
      const float* p = gW + (size_t)k * NDIM + nq * 4;
      const f32x4 w0 = *(const f32x4*)p;
      const f32x4 w1 = *(const f32x4*)(p + NDIM);
      #pragma unroll
      for (int j = 0; j < 4; ++j) {
        bf16x2 pk = { (__bf16)w0[j], (__bf16)w1[j] };
        *(bf16x2*)&wlds[(nq * 4 + j) * KPAD + k] = pk;   // 4B-aligned (k even)
      }
    }
  }
  // Every LDS address read below is staged (rows<=99, k<=399 via clamps):
  // no zero-fill needed. Full __syncthreads(): real fence (round-4 lesson).
  __syncthreads();

  f32x4 acc[2][7];
  #pragma unroll
  for (int m = 0; m < 2; ++m)
    #pragma unroll
    for (int n = 0; n < 7; ++n) acc[m][n] = f32x4{0, 0, 0, 0};

  // ---- main loop: ZERO barriers; W read-only in LDS; A streams via registers ----
  #pragma unroll
  for (int t = 0; t < NSTEP; ++t) {
    const int pp = t & 1;
    bf16x8 a0, a1;
    #pragma unroll
    for (int j = 0; j < 4; ++j) {            // vmcnt wait for A(t) lands here
      a0[j]     = (__bf16)areg[pp][0][0][j];
      a0[4 + j] = (__bf16)areg[pp][0][1][j];
      a1[j]     = (__bf16)areg[pp][1][0][j];
      a1[4 + j] = (__bf16)areg[pp][1][1][j];
    }
    if (t + 2 < NSTEP) LOADA(t + 2);         // reissue freed slot (after cvt: WAR safe)
    // K-clamp: lanes that clamp (t=12, kg>=16) have A==0 -> finite B is enough.
    const int kb2  = t * BK + kg;
    const int koff = (kb2 <= KDIM - 8) ? kb2 : (KDIM - 8);
    #pragma unroll
    for (int n = 0; n < 7; ++n) {
      // n=6 row-clamp: cols 96..99 (rl<4) get true rows 96..99; cols 100..111
      // read duplicated rows (finite garbage) and are never stored.
      const int brow = n * 16 + (n == 6 ? (rl & 3) : rl);
      bf16x8 b = *(const bf16x8*)&wlds[brow * KPAD + koff];
      acc[0][n] = __builtin_amdgcn_mfma_f32_16x16x32_bf16(a0, b, acc[0][n], 0, 0, 0);
      acc[1][n] = __builtin_amdgcn_mfma_f32_16x16x32_bf16(a1, b, acc[1][n], 0, 0, 0);
    }
  }

  // ---- epilogue: C/D map (16x16 family): col = lane&15, row = (lane>>4)*4 + reg ----
  const float* gB = bias + (size_t)c * NDIM;
  float* gO = out + (size_t)c * NDIM;
  #pragma unroll
  for (int n = 0; n < 7; ++n) {
    const int col = n * 16 + rl;
    if (col < NDIM) {
      const float bv = gB[col];
      #pragma unroll
      for (int m = 0; m < 2; ++m) {
        const int r0 = wave * 32 + m * 16 + (lane >> 4) * 4;
        #pragma unroll
        for (int j = 0; j < 4; ++j) {
          gO[(size_t)(r0 + j) * (NCAT * NDIM) + col] = acc[m][n][j] + bv;
        }
      }
    }
  }
}

extern "C" void kernel_launch(void* const* d_in, const int* in_sizes, int n_in,
                              void* d_out, int out_size, void* d_ws, size_t ws_size,
                              hipStream_t stream) {
  const float* in   = (const float*)d_in[0];
  const float* wt   = (const float*)d_in[1];
  const float* bias = (const float*)d_in[2];
  float* o          = (float*)d_out;
  cat_dense<<<dim3(NCAT), dim3(512), 0, stream>>>(in, wt, bias, o);
}